// Round 7
// baseline (586.293 us; speedup 1.0000x reference)
//
#include <hip/hip_runtime.h>

#define B_ 16
#define N_ 2048
#define IN_ 12
#define H_ 64
#define K_ 16

// Skewed LDS index: row-major [r][k] tiles, stride 68 + 4-float skew per 4 rows.
#define IDX(r, k) ((r) * 68 + ((r) >> 2) * 4 + (k))

// ---------------------------------------------------------------------------
// Kernel A: emb = relu(x@W1+b1)@W2+b2 (one wave per row); sref = 1/max(||e||,eps)
// (byte-identical to round 4 — passing arithmetic, do not modify)
// ---------------------------------------------------------------------------
__global__ __launch_bounds__(256) void emb_kernel(
    const float* __restrict__ x, const float* __restrict__ W1,
    const float* __restrict__ b1, const float* __restrict__ W2,
    const float* __restrict__ b2, float* __restrict__ emb_out,
    float* __restrict__ sref) {
  const int lane = threadIdx.x & 63;
  const int wid = threadIdx.x >> 6;
  const long long row = (long long)blockIdx.x * 4 + wid;  // 0..32767

  const float* xr = x + row * IN_;
  float xv[IN_];
#pragma unroll
  for (int k = 0; k < IN_; ++k) xv[k] = xr[k];

  float acc = b1[lane];
#pragma unroll
  for (int k = 0; k < IN_; ++k) acc += xv[k] * W1[k * H_ + lane];
  float h = fmaxf(acc, 0.f);

  float e = b2[lane];
#pragma unroll
  for (int j = 0; j < H_; ++j) {
    float hj = __shfl(h, j, 64);
    e += hj * W2[j * H_ + lane];
  }

  float ss = e * e;
#pragma unroll
  for (int off = 32; off; off >>= 1) ss += __shfl_xor(ss, off, 64);
  float s = 1.0f / fmaxf(sqrtf(ss), 1e-12f);

  emb_out[row * H_ + lane] = e;
  if (lane == 0) sref[row] = s;
}

// ---------------------------------------------------------------------------
// Fused sim+topk. One block per 64-row stripe; 16 column-tiles of 128.
// Sim values bit-identical to round 4: A staged as fl(e*s_i) (per-element
// rounding), B raw, float4 FMA chains over dg=0..15 ascending, epilogue
// (x+y+z+w)*s_j. Selection: u64 key = mono(v)<<32 | (N-1-j) (proven
// comparator), running top-16 per row in a lane-distributed sorted rank
// list (lane tx of the 16-lane row-group holds rank tx, named kr0..kr3 for
// the group's 4 rows). Insert: group-max pop -> ballot position -> shfl_up
// shift. Winners' value/index recovered exactly from the key at the end.
// ---------------------------------------------------------------------------
__device__ __forceinline__ unsigned mono32(float v) {
  unsigned u = __float_as_uint(v);
  return u ^ ((unsigned)((int)u >> 31) | 0x80000000u);
}

#define MKKEY(A4, SJ, J)                                                      \
  ((((unsigned long long)mono32(                                              \
        ((A4).x + (A4).y + (A4).z + (A4).w) * (SJ)))                          \
    << 32) |                                                                  \
   (unsigned)(N_ - 1 - (J)))

// Merge this tile's 8 candidate keys (ck[0..7], static-indexed) of one row
// into the row's distributed rank list KR. Group-uniform while loop.
#define MERGE_ROW(KR)                                                         \
  {                                                                           \
    unsigned cons = 0u;                                                       \
    unsigned long long cmax = 0ull;                                           \
    _Pragma("unroll") for (int q = 0; q < 8; ++q)                             \
        if (ck[q] > cmax) cmax = ck[q];                                       \
    unsigned long long tau = __shfl(KR, 15, 16);                              \
    while (((__ballot(cmax > tau) >> gsh) & 0xFFFFull) != 0ull) {             \
      unsigned long long bk = cmax;                                           \
      _Pragma("unroll") for (int off = 8; off; off >>= 1) {                   \
        const unsigned long long ok = __shfl_xor(bk, off, 16);                \
        if (ok > bk) bk = ok;                                                 \
      }                                                                       \
      const int pos =                                                         \
          __popc((unsigned)((__ballot(KR > bk) >> gsh) & 0xFFFFull));         \
      const unsigned long long up = __shfl_up(KR, 1, 16);                     \
      KR = (tx == pos) ? bk : (tx > pos ? up : KR);                           \
      if (cmax == bk) {                                                       \
        unsigned long long nm = 0ull;                                         \
        _Pragma("unroll") for (int q = 0; q < 8; ++q) {                       \
          if (ck[q] == bk) cons |= (1u << q);                                 \
          if (!((cons >> q) & 1u) && ck[q] > nm) nm = ck[q];                  \
        }                                                                     \
        cmax = nm;                                                            \
      }                                                                       \
      tau = __shfl(KR, 15, 16);                                               \
    }                                                                         \
  }

#define FMA_ROW(ACC, AV)                                                      \
  _Pragma("unroll") for (int q = 0; q < 8; ++q) {                             \
    ACC[q].x += (AV).x * bv[q].x;                                             \
    ACC[q].y += (AV).y * bv[q].y;                                             \
    ACC[q].z += (AV).z * bv[q].z;                                             \
    ACC[q].w += (AV).w * bv[q].w;                                             \
  }

__global__ __launch_bounds__(256) void fused_kernel(
    const float* __restrict__ emb, const float* __restrict__ sref,
    float* __restrict__ adj) {
  __shared__ float As[4408];  // 64 rows, pre-scaled  (IDX(63,63)+1)
  __shared__ float Bs[8824];  // 128 rows, raw        (IDX(127,63)+1)

  const int t = threadIdx.x;
  const int b = blockIdx.x >> 5;          // 32 stripes per batch
  const int i0 = (blockIdx.x & 31) * 64;  // stripe base row

  const float* Eb = emb + (size_t)b * N_ * H_;
  const float* srb = sref + b * N_;

  // ---- stage A-stripe once: 64 rows, pre-scaled by s_i ----
  {
    const int r = t >> 2;            // 0..63
    const int k0 = (t & 3) * 16;
    const float sA = srb[i0 + r];
    const float* src = Eb + (size_t)(i0 + r) * H_ + k0;
#pragma unroll
    for (int i = 0; i < 4; ++i) {
      const float4 v = *(const float4*)(src + i * 4);
      float4 w;
      w.x = v.x * sA; w.y = v.y * sA; w.z = v.z * sA; w.w = v.w * sA;
      *(float4*)&As[IDX(r, k0 + i * 4)] = w;
    }
  }

  const int tx = t & 15, ty = t >> 4;
  const int r0 = ty * 4;                 // group's first row (0..60)
  const int gsh = (t & 63) & 0x30;       // group base lane within wave

  unsigned long long kr0 = 0ull, kr1 = 0ull, kr2 = 0ull, kr3 = 0ull;

  int bof[8];
#pragma unroll
  for (int q = 0; q < 4; ++q) {
    bof[q] = IDX(tx * 4 + q, 0);
    bof[q + 4] = IDX(64 + tx * 4 + q, 0);
  }
  const int aof0 = IDX(r0 + 0, 0), aof1 = IDX(r0 + 1, 0);
  const int aof2 = IDX(r0 + 2, 0), aof3 = IDX(r0 + 3, 0);

  for (int tj = 0; tj < N_ / 128; ++tj) {
    __syncthreads();  // prior tile's Bs reads done (covers A-stage on tj=0)
    // ---- stage B-tile: 128 rows, raw ----
    {
      const int r = t >> 1;            // 0..127
      const int k0 = (t & 1) * 32;
      const float* src = Eb + (size_t)(tj * 128 + r) * H_ + k0;
#pragma unroll
      for (int i = 0; i < 8; ++i) {
        const float4 v = *(const float4*)(src + i * 4);
        *(float4*)&Bs[IDX(r, k0 + i * 4)] = v;
      }
    }
    __syncthreads();

    float4 a0[8], a1[8], a2[8], a3[8];
#pragma unroll
    for (int q = 0; q < 8; ++q) {
      a0[q] = make_float4(0.f, 0.f, 0.f, 0.f);
      a1[q] = make_float4(0.f, 0.f, 0.f, 0.f);
      a2[q] = make_float4(0.f, 0.f, 0.f, 0.f);
      a3[q] = make_float4(0.f, 0.f, 0.f, 0.f);
    }

#pragma unroll 4
    for (int dg = 0; dg < 16; ++dg) {
      const float4 av0 = *(const float4*)&As[aof0 + dg * 4];
      const float4 av1 = *(const float4*)&As[aof1 + dg * 4];
      const float4 av2 = *(const float4*)&As[aof2 + dg * 4];
      const float4 av3 = *(const float4*)&As[aof3 + dg * 4];
      float4 bv[8];
#pragma unroll
      for (int q = 0; q < 8; ++q) bv[q] = *(const float4*)&Bs[bof[q] + dg * 4];
      FMA_ROW(a0, av0);
      FMA_ROW(a1, av1);
      FMA_ROW(a2, av2);
      FMA_ROW(a3, av3);
    }

    // ---- epilogue + merge (per row; cols jb..jb+3 and jb+64..jb+67) ----
    const int jb = tj * 128 + tx * 4;
    const float4 sj0 = *(const float4*)(srb + jb);
    const float4 sj1 = *(const float4*)(srb + jb + 64);

    unsigned long long ck[8];
    ck[0] = MKKEY(a0[0], sj0.x, jb + 0);
    ck[1] = MKKEY(a0[1], sj0.y, jb + 1);
    ck[2] = MKKEY(a0[2], sj0.z, jb + 2);
    ck[3] = MKKEY(a0[3], sj0.w, jb + 3);
    ck[4] = MKKEY(a0[4], sj1.x, jb + 64);
    ck[5] = MKKEY(a0[5], sj1.y, jb + 65);
    ck[6] = MKKEY(a0[6], sj1.z, jb + 66);
    ck[7] = MKKEY(a0[7], sj1.w, jb + 67);
    MERGE_ROW(kr0);

    ck[0] = MKKEY(a1[0], sj0.x, jb + 0);
    ck[1] = MKKEY(a1[1], sj0.y, jb + 1);
    ck[2] = MKKEY(a1[2], sj0.z, jb + 2);
    ck[3] = MKKEY(a1[3], sj0.w, jb + 3);
    ck[4] = MKKEY(a1[4], sj1.x, jb + 64);
    ck[5] = MKKEY(a1[5], sj1.y, jb + 65);
    ck[6] = MKKEY(a1[6], sj1.z, jb + 66);
    ck[7] = MKKEY(a1[7], sj1.w, jb + 67);
    MERGE_ROW(kr1);

    ck[0] = MKKEY(a2[0], sj0.x, jb + 0);
    ck[1] = MKKEY(a2[1], sj0.y, jb + 1);
    ck[2] = MKKEY(a2[2], sj0.z, jb + 2);
    ck[3] = MKKEY(a2[3], sj0.w, jb + 3);
    ck[4] = MKKEY(a2[4], sj1.x, jb + 64);
    ck[5] = MKKEY(a2[5], sj1.y, jb + 65);
    ck[6] = MKKEY(a2[6], sj1.z, jb + 66);
    ck[7] = MKKEY(a2[7], sj1.w, jb + 67);
    MERGE_ROW(kr2);

    ck[0] = MKKEY(a3[0], sj0.x, jb + 0);
    ck[1] = MKKEY(a3[1], sj0.y, jb + 1);
    ck[2] = MKKEY(a3[2], sj0.z, jb + 2);
    ck[3] = MKKEY(a3[3], sj0.w, jb + 3);
    ck[4] = MKKEY(a3[4], sj1.x, jb + 64);
    ck[5] = MKKEY(a3[5], sj1.y, jb + 65);
    ck[6] = MKKEY(a3[6], sj1.z, jb + 66);
    ck[7] = MKKEY(a3[7], sj1.w, jb + 67);
    MERGE_ROW(kr3);
  }

  // ---- write stripe: zeros, barrier (drains vmcnt), then scatter winners ----
  float* stripe = adj + ((size_t)b * N_ + i0) * N_;
  const float4 z4 = make_float4(0.f, 0.f, 0.f, 0.f);
  for (int idx = t; idx < 64 * (N_ / 4); idx += 256)
    ((float4*)stripe)[idx] = z4;
  __syncthreads();

#define SCATTER(KR, R2)                                                       \
  {                                                                           \
    const int j = N_ - 1 - (int)(KR & 0xFFFFFFFFull);                         \
    const unsigned m = (unsigned)(KR >> 32);                                  \
    const unsigned u = (m & 0x80000000u) ? (m ^ 0x80000000u) : ~m;            \
    stripe[(size_t)(r0 + (R2)) * N_ + j] = __uint_as_float(u);                \
  }
  SCATTER(kr0, 0);
  SCATTER(kr1, 1);
  SCATTER(kr2, 2);
  SCATTER(kr3, 3);
}

extern "C" void kernel_launch(void* const* d_in, const int* in_sizes, int n_in,
                              void* d_out, int out_size, void* d_ws, size_t ws_size,
                              hipStream_t stream) {
  const float* x  = (const float*)d_in[0];
  const float* W1 = (const float*)d_in[1];
  const float* b1 = (const float*)d_in[2];
  const float* W2 = (const float*)d_in[3];
  const float* b2 = (const float*)d_in[4];

  float* adj  = (float*)d_out;                              // B*N*N
  float* embo = (float*)d_out + (size_t)B_ * N_ * N_;       // B*N*H
  float* sref = (float*)d_ws;                               // B*N floats

  emb_kernel<<<(B_ * N_) / 4, 256, 0, stream>>>(x, W1, b1, W2, b2, embo, sref);
  fused_kernel<<<B_ * (N_ / 64), 256, 0, stream>>>(embo, sref, adj);
}

// Round 8
// 420.654 us; speedup vs baseline: 1.3938x; 1.3938x over previous
//
#include <hip/hip_runtime.h>

#define B_ 16
#define N_ 2048
#define IN_ 12
#define H_ 64
#define K_ 16

// Skewed LDS index: row-major [r][k] tiles, stride 68 + 4-float skew per 4 rows.
#define IDX(r, k) ((r) * 68 + ((r) >> 2) * 4 + (k))

// ---------------------------------------------------------------------------
// Kernel A: emb = relu(x@W1+b1)@W2+b2 (one wave per row); sref = 1/max(||e||,eps)
// (byte-identical to round 4 — passing arithmetic, do not modify)
// ---------------------------------------------------------------------------
__global__ __launch_bounds__(256) void emb_kernel(
    const float* __restrict__ x, const float* __restrict__ W1,
    const float* __restrict__ b1, const float* __restrict__ W2,
    const float* __restrict__ b2, float* __restrict__ emb_out,
    float* __restrict__ sref) {
  const int lane = threadIdx.x & 63;
  const int wid = threadIdx.x >> 6;
  const long long row = (long long)blockIdx.x * 4 + wid;  // 0..32767

  const float* xr = x + row * IN_;
  float xv[IN_];
#pragma unroll
  for (int k = 0; k < IN_; ++k) xv[k] = xr[k];

  float acc = b1[lane];
#pragma unroll
  for (int k = 0; k < IN_; ++k) acc += xv[k] * W1[k * H_ + lane];
  float h = fmaxf(acc, 0.f);

  float e = b2[lane];
#pragma unroll
  for (int j = 0; j < H_; ++j) {
    float hj = __shfl(h, j, 64);
    e += hj * W2[j * H_ + lane];
  }

  float ss = e * e;
#pragma unroll
  for (int off = 32; off; off >>= 1) ss += __shfl_xor(ss, off, 64);
  float s = 1.0f / fmaxf(sqrtf(ss), 1e-12f);

  emb_out[row * H_ + lane] = e;
  if (lane == 0) sref[row] = s;
}

// ---------------------------------------------------------------------------
// Fused sim+topk, round-8 decomposition: 16-row stripes (2048 blocks),
// one row per 16-lane group (16 groups/block) -> the 4 groups of a wave
// merge in PARALLEL. Sim values bit-identical to round 4: A staged as
// fl(e*s_i), B raw, float4 FMA chains over dg=0..15 ascending, epilogue
// (x+y+z+w)*s_j. Selection: u64 key = mono(v)<<32 | (N-1-j); running
// top-16 in a lane-distributed sorted rank list (lane tx holds rank tx).
// ---------------------------------------------------------------------------
__device__ __forceinline__ unsigned mono32(float v) {
  unsigned u = __float_as_uint(v);
  return u ^ ((unsigned)((int)u >> 31) | 0x80000000u);
}

#define MKKEY(A4, SJ, J)                                                      \
  ((((unsigned long long)mono32(                                              \
        ((A4).x + (A4).y + (A4).z + (A4).w) * (SJ)))                          \
    << 32) |                                                                  \
   (unsigned)(N_ - 1 - (J)))

// Merge this tile's 8 candidate keys (ck[0..7]) of this group's row into the
// distributed rank list KR. Group-uniform while loop (proven in round 7).
#define MERGE_ROW(KR)                                                         \
  {                                                                           \
    unsigned cons = 0u;                                                       \
    unsigned long long cmax = 0ull;                                           \
    _Pragma("unroll") for (int q = 0; q < 8; ++q)                             \
        if (ck[q] > cmax) cmax = ck[q];                                       \
    unsigned long long tau = __shfl(KR, 15, 16);                              \
    while (((__ballot(cmax > tau) >> gsh) & 0xFFFFull) != 0ull) {             \
      unsigned long long bk = cmax;                                           \
      _Pragma("unroll") for (int off = 8; off; off >>= 1) {                   \
        const unsigned long long ok = __shfl_xor(bk, off, 16);                \
        if (ok > bk) bk = ok;                                                 \
      }                                                                       \
      const int pos =                                                         \
          __popc((unsigned)((__ballot(KR > bk) >> gsh) & 0xFFFFull));         \
      const unsigned long long up = __shfl_up(KR, 1, 16);                     \
      KR = (tx == pos) ? bk : (tx > pos ? up : KR);                           \
      if (cmax == bk) {                                                       \
        unsigned long long nm = 0ull;                                         \
        _Pragma("unroll") for (int q = 0; q < 8; ++q) {                       \
          if (ck[q] == bk) cons |= (1u << q);                                 \
          if (!((cons >> q) & 1u) && ck[q] > nm) nm = ck[q];                  \
        }                                                                     \
        cmax = nm;                                                            \
      }                                                                       \
      tau = __shfl(KR, 15, 16);                                               \
    }                                                                         \
  }

__global__ __launch_bounds__(256) void fused_kernel(
    const float* __restrict__ emb, const float* __restrict__ sref,
    float* __restrict__ adj) {
  __shared__ float As[1096];  // 16 rows, pre-scaled (IDX(15,63)+1)
  __shared__ float Bs[8824];  // 128 rows, raw       (IDX(127,63)+1)

  const int t = threadIdx.x;
  const int b = blockIdx.x >> 7;           // 128 stripes per batch
  const int i0 = (blockIdx.x & 127) * 16;  // stripe base row

  const float* Eb = emb + (size_t)b * N_ * H_;
  const float* srb = sref + b * N_;

  const int tx = t & 15, ty = t >> 4;      // group ty owns row i0+ty
  const int gsh = (t & 63) & 0x30;         // group base lane within wave

  // ---- stage A-stripe once: 16 rows, pre-scaled by s_i (one float4/thread)
  {
    const int r = ty;
    const int k0 = tx * 4;
    const float sA = srb[i0 + r];
    const float4 v = *(const float4*)(Eb + (size_t)(i0 + r) * H_ + k0);
    float4 w;
    w.x = v.x * sA; w.y = v.y * sA; w.z = v.z * sA; w.w = v.w * sA;
    *(float4*)&As[IDX(r, k0)] = w;
  }

  const int aof = IDX(ty, 0);
  int bof[8];
#pragma unroll
  for (int q = 0; q < 4; ++q) {
    bof[q] = IDX(tx * 4 + q, 0);
    bof[q + 4] = IDX(64 + tx * 4 + q, 0);
  }

  unsigned long long kr = 0ull;  // rank-tx key of this group's row

  for (int tj = 0; tj < N_ / 128; ++tj) {
    __syncthreads();  // prior tile's Bs reads done (covers A-stage on tj=0)
    // ---- stage B-tile: 128 rows, raw ----
    {
      const int r = t >> 1;
      const int k0 = (t & 1) * 32;
      const float* src = Eb + (size_t)(tj * 128 + r) * H_ + k0;
#pragma unroll
      for (int i = 0; i < 8; ++i) {
        const float4 v = *(const float4*)(src + i * 4);
        *(float4*)&Bs[IDX(r, k0 + i * 4)] = v;
      }
    }
    __syncthreads();

    float4 a[8];
#pragma unroll
    for (int q = 0; q < 8; ++q) a[q] = make_float4(0.f, 0.f, 0.f, 0.f);

#pragma unroll 4
    for (int dg = 0; dg < 16; ++dg) {
      const float4 av = *(const float4*)&As[aof + dg * 4];
      float4 bv[8];
#pragma unroll
      for (int q = 0; q < 8; ++q) bv[q] = *(const float4*)&Bs[bof[q] + dg * 4];
#pragma unroll
      for (int q = 0; q < 8; ++q) {
        a[q].x += av.x * bv[q].x;
        a[q].y += av.y * bv[q].y;
        a[q].z += av.z * bv[q].z;
        a[q].w += av.w * bv[q].w;
      }
    }

    // ---- epilogue + merge (cols jb..jb+3 and jb+64..jb+67) ----
    const int jb = tj * 128 + tx * 4;
    const float4 sj0 = *(const float4*)(srb + jb);
    const float4 sj1 = *(const float4*)(srb + jb + 64);

    unsigned long long ck[8];
    ck[0] = MKKEY(a[0], sj0.x, jb + 0);
    ck[1] = MKKEY(a[1], sj0.y, jb + 1);
    ck[2] = MKKEY(a[2], sj0.z, jb + 2);
    ck[3] = MKKEY(a[3], sj0.w, jb + 3);
    ck[4] = MKKEY(a[4], sj1.x, jb + 64);
    ck[5] = MKKEY(a[5], sj1.y, jb + 65);
    ck[6] = MKKEY(a[6], sj1.z, jb + 66);
    ck[7] = MKKEY(a[7], sj1.w, jb + 67);
    MERGE_ROW(kr);
  }

  // ---- write stripe: zeros, barrier (drains vmcnt), then scatter winners ----
  float* stripe = adj + ((size_t)b * N_ + i0) * N_;
  const float4 z4 = make_float4(0.f, 0.f, 0.f, 0.f);
#pragma unroll
  for (int it = 0; it < (16 * N_ / 4) / 256; ++it)
    ((float4*)stripe)[it * 256 + t] = z4;
  __syncthreads();

  // each thread scatters rank tx of row ty; value recovered exactly from key
  {
    const int j = N_ - 1 - (int)(kr & 0xFFFFFFFFull);
    const unsigned m = (unsigned)(kr >> 32);
    const unsigned u = (m & 0x80000000u) ? (m ^ 0x80000000u) : ~m;
    stripe[(size_t)ty * N_ + j] = __uint_as_float(u);
  }
}

extern "C" void kernel_launch(void* const* d_in, const int* in_sizes, int n_in,
                              void* d_out, int out_size, void* d_ws, size_t ws_size,
                              hipStream_t stream) {
  const float* x  = (const float*)d_in[0];
  const float* W1 = (const float*)d_in[1];
  const float* b1 = (const float*)d_in[2];
  const float* W2 = (const float*)d_in[3];
  const float* b2 = (const float*)d_in[4];

  float* adj  = (float*)d_out;                              // B*N*N
  float* embo = (float*)d_out + (size_t)B_ * N_ * N_;       // B*N*H
  float* sref = (float*)d_ws;                               // B*N floats

  emb_kernel<<<(B_ * N_) / 4, 256, 0, stream>>>(x, W1, b1, W2, b2, embo, sref);
  fused_kernel<<<B_ * (N_ / 16), 256, 0, stream>>>(embo, sref, adj);
}